// Round 1
// baseline (918.096 us; speedup 1.0000x reference)
//
#include <hip/hip_runtime.h>

// Problem constants (match reference setup_inputs()).
#define BATCH  8192
#define BOX    10
#define PAIR   90          // BOX*(BOX-1)
#define NUM_QT 65
#define NUM_OT 151
#define N_OUT  (NUM_QT * PAIR * NUM_OT * NUM_OT)   // 133,385,850 floats (~533 MB)

// Grid-stride float4 streaming copy: out = score_matrix.
// N_OUT % 4 == 2, so a 2-element tail is handled by block 0.
__global__ void copy_kernel(const float* __restrict__ src,
                            float* __restrict__ dst,
                            int n4 /* number of full float4s */) {
    const float4* __restrict__ s4 = (const float4*)src;
    float4* __restrict__ d4 = (float4*)dst;
    int stride = gridDim.x * blockDim.x;
    for (int i = blockIdx.x * blockDim.x + threadIdx.x; i < n4; i += stride)
        d4[i] = s4[i];
    // tail: elements [n4*4, N_OUT)
    if (blockIdx.x == 0 && threadIdx.x < (N_OUT - n4 * 4)) {
        int i = n4 * 4 + threadIdx.x;
        dst[i] = src[i];
    }
}

// One thread per (batch, pair). Decodes the static off-diagonal pair order:
// pair p = i*(BOX-1)+k, with column j = (k < i) ? k : k+1  (skip the diagonal).
//   ol1 = obj_label[b, j], ol2 = obj_label[b, i], val = att[b,j]*att[b,i]
// Scatter-add into out[q, p, ol1, ol2].
__global__ void scatter_add_kernel(const int* __restrict__ obj_label,
                                   const int* __restrict__ qus_type,
                                   const float* __restrict__ attention,
                                   float* __restrict__ out) {
    int t = blockIdx.x * blockDim.x + threadIdx.x;
    if (t >= BATCH * PAIR) return;
    int b = t / PAIR;
    int p = t - b * PAIR;
    int i = p / (BOX - 1);
    int k = p - i * (BOX - 1);
    int j = (k < i) ? k : k + 1;

    int q  = qus_type[b];
    int o1 = obj_label[b * BOX + j];
    int o2 = obj_label[b * BOX + i];
    float v = attention[b * BOX + j] * attention[b * BOX + i];

    size_t idx = (((size_t)q * PAIR + p) * NUM_OT + (size_t)o1) * NUM_OT + (size_t)o2;
    atomicAdd(&out[idx], v);
}

extern "C" void kernel_launch(void* const* d_in, const int* in_sizes, int n_in,
                              void* d_out, int out_size, void* d_ws, size_t ws_size,
                              hipStream_t stream) {
    const int*   obj_label    = (const int*)d_in[0];   // [BATCH, BOX] int32
    const int*   qus_type     = (const int*)d_in[1];   // [BATCH] int32
    const float* attention    = (const float*)d_in[2]; // [BATCH, BOX] fp32
    const float* score_matrix = (const float*)d_in[3]; // [NUM_QT, PAIR, NUM_OT, NUM_OT] fp32
    float* out = (float*)d_out;

    // Shader-based streaming copy (hipMemcpyAsync D2D takes the slow
    // SDMA/blit path under graph capture: ~1.2 TB/s vs ~6 TB/s shader copy).
    const int n4 = N_OUT / 4;           // 33,346,462 full float4s (+2 tail)
    copy_kernel<<<2048, 256, 0, stream>>>(score_matrix, out, n4);

    // Scatter-add after the copy on the same stream (ordering required:
    // atomics must land on the copied values).
    const int total = BATCH * PAIR;
    const int block = 256;
    const int grid  = (total + block - 1) / block;
    scatter_add_kernel<<<grid, block, 0, stream>>>(obj_label, qus_type, attention, out);
}